// Round 1
// baseline (23278.619 us; speedup 1.0000x reference)
//
#include <hip/hip_runtime.h>
#include <stdint.h>

typedef short s16x8 __attribute__((ext_vector_type(8)));
typedef float f32x4 __attribute__((ext_vector_type(4)));
typedef unsigned short u16;

#define DEV static __device__ __forceinline__

DEV u16 f2bf(float f) {
  unsigned u = __float_as_uint(f);
  u = (u + 0x7FFFu + ((u >> 16) & 1u)) >> 16;   // RNE
  return (u16)u;
}
DEV float sigf(float x) { return 1.0f / (1.0f + __expf(-x)); }
DEV float tanh_(float x) { float e = __expf(2.0f * x); return 1.0f - 2.0f / (e + 1.0f); }
DEV f32x4 MFMA(s16x8 a, s16x8 b, f32x4 c) {
  return __builtin_amdgcn_mfma_f32_16x16x32_bf16(a, b, c, 0, 0, 0);
}

// ---------------- problem dims ----------------
constexpr int Bz = 256, INz = 512, Hz = 1024, Oz = 128;
constexpr int G4 = 4096;     // 4*H
constexpr int TB = 512;      // beat timesteps (M*S)
constexpr int BM = 8192;     // B*M rows

// ---------------- workspace layout (bytes) ----------------
constexpr size_t OFF_XG   = 0;                                   // f32 [8192][4096] (measure xg, then beat lat-xg)
constexpr size_t OFF_LATB = OFF_XG   + (size_t)BM * G4 * 4;      // bf16 [8192][512]
constexpr size_t OFF_INPB = OFF_LATB + (size_t)BM * INz * 2;     // bf16 [256*512][128]
constexpr size_t OFF_MWIH = OFF_INPB + (size_t)Bz * TB * Oz * 2; // bf16 [4096][512]
constexpr size_t OFF_MWHH = OFF_MWIH + (size_t)G4 * INz * 2;     // bf16 [4096][1024]
constexpr size_t OFF_BWA  = OFF_MWHH + (size_t)G4 * Hz * 2;      // bf16 [4096][1024]
constexpr size_t OFF_BWB  = OFF_BWA  + (size_t)G4 * Hz * 2;      // bf16 [4096][128]
constexpr size_t OFF_BWHH = OFF_BWB  + (size_t)G4 * Oz * 2;      // bf16 [4096][1024]
constexpr size_t OFF_LINW = OFF_BWHH + (size_t)G4 * Hz * 2;      // bf16 [128][1024]
constexpr size_t OFF_LAT  = OFF_LINW + (size_t)Oz * Hz * 2;      // bf16 [8192][1024] tanh(h) of measure LSTM
constexpr size_t OFF_HM   = OFF_LAT  + (size_t)BM * Hz * 2;      // bf16 2x[256][1024]
constexpr size_t OFF_HB   = OFF_HM   + (size_t)2 * Bz * Hz * 2;  // bf16 2x[256][1024]
constexpr size_t OFF_RING = OFF_HB   + (size_t)2 * Bz * Hz * 2;  // bf16 [32][256][1024] tanh(h) ring
constexpr size_t OFF_CTR  = OFF_RING + (size_t)32 * Bz * Hz * 2; // counters
// total ~242.5 MB

// ================= prep: casts / splits / zeroing =================
__global__ __launch_bounds__(256) void prep_kernel(
    char* __restrict__ ws, const float* __restrict__ latent,
    const float* __restrict__ inputs, const float* __restrict__ mWih,
    const float* __restrict__ mWhh, const float* __restrict__ bWih,
    const float* __restrict__ bWhh, const float* __restrict__ linW)
{
  size_t i = (size_t)blockIdx.x * 256 + threadIdx.x;
  const size_t n0 = (size_t)BM * INz;        // latent
  const size_t n1 = (size_t)Bz * TB * Oz;    // inputs
  const size_t n2 = (size_t)G4 * INz;        // mWih
  const size_t n3 = (size_t)G4 * Hz;         // mWhh
  const size_t n4 = (size_t)G4 * (Hz + Oz);  // bWih (split)
  const size_t n5 = (size_t)G4 * Hz;         // bWhh
  const size_t n6 = (size_t)Oz * Hz;         // linW
  const size_t n7 = (size_t)2 * Bz * Hz;     // zero h_m
  const size_t n8 = (size_t)2 * Bz * Hz;     // zero h_b
  const size_t n9 = 64;                      // counters
  if (i < n0) { ((u16*)(ws + OFF_LATB))[i] = f2bf(latent[i]); return; } i -= n0;
  if (i < n1) { ((u16*)(ws + OFF_INPB))[i] = f2bf(inputs[i]); return; } i -= n1;
  if (i < n2) { ((u16*)(ws + OFF_MWIH))[i] = f2bf(mWih[i]);   return; } i -= n2;
  if (i < n3) { ((u16*)(ws + OFF_MWHH))[i] = f2bf(mWhh[i]);   return; } i -= n3;
  if (i < n4) {
    size_t r = i / 1152, c = i - r * 1152;
    float v = bWih[i];
    if (c < 1024) ((u16*)(ws + OFF_BWA))[r * 1024 + c] = f2bf(v);
    else          ((u16*)(ws + OFF_BWB))[r * 128 + (c - 1024)] = f2bf(v);
    return;
  } i -= n4;
  if (i < n5) { ((u16*)(ws + OFF_BWHH))[i] = f2bf(bWhh[i]);   return; } i -= n5;
  if (i < n6) { ((u16*)(ws + OFF_LINW))[i] = f2bf(linW[i]);   return; } i -= n6;
  if (i < n7) { ((u16*)(ws + OFF_HM))[i] = 0; return; } i -= n7;
  if (i < n8) { ((u16*)(ws + OFF_HB))[i] = 0; return; } i -= n8;
  if (i < n9) { ((unsigned*)(ws + OFF_CTR))[i] = 0; return; }
}

// ================= projection GEMM: C[M][N](f32) = A[M][K](bf16) @ B[N][K]^T + bias =================
__global__ __launch_bounds__(256) void gemm_bt_bias(
    const u16* __restrict__ A, const u16* __restrict__ Bw,
    const float* __restrict__ bias, float* __restrict__ C, int K, int Ndim)
{
  __shared__ u16 As[128 * 40];   // pad 32->40: conflict-free frag reads
  __shared__ u16 Bs[128 * 40];
  const int bx = blockIdx.x & 63;         // M/128 = 64
  const int by = blockIdx.x >> 6;         // N/128 = 32
  const int m0 = bx * 128, n0 = by * 128;
  const int tid = threadIdx.x, lane = tid & 63, wave = tid >> 6;
  const int quad = lane >> 4, l15 = lane & 15;
  const int wm = wave & 1, wn = wave >> 1;
  const int srow = tid >> 1, shalf = tid & 1;

  f32x4 acc[4][4];
  #pragma unroll
  for (int mi = 0; mi < 4; ++mi)
    #pragma unroll
    for (int ni = 0; ni < 4; ++ni) { f32x4 z = {0.f,0.f,0.f,0.f}; acc[mi][ni] = z; }

  const int KC = K >> 5;
  for (int kc = 0; kc < KC; ++kc) {
    const size_t ka = (size_t)(m0 + srow) * K + kc * 32 + shalf * 16;
    s16x8 va0 = *(const s16x8*)(A + ka);
    s16x8 va1 = *(const s16x8*)(A + ka + 8);
    const size_t kb = (size_t)(n0 + srow) * K + kc * 32 + shalf * 16;
    s16x8 vb0 = *(const s16x8*)(Bw + kb);
    s16x8 vb1 = *(const s16x8*)(Bw + kb + 8);
    __syncthreads();
    *(s16x8*)(As + srow * 40 + shalf * 16)     = va0;
    *(s16x8*)(As + srow * 40 + shalf * 16 + 8) = va1;
    *(s16x8*)(Bs + srow * 40 + shalf * 16)     = vb0;
    *(s16x8*)(Bs + srow * 40 + shalf * 16 + 8) = vb1;
    __syncthreads();
    s16x8 af[4], bf[4];
    #pragma unroll
    for (int mi = 0; mi < 4; ++mi)
      af[mi] = *(const s16x8*)(As + (wm * 64 + mi * 16 + l15) * 40 + quad * 8);
    #pragma unroll
    for (int ni = 0; ni < 4; ++ni)
      bf[ni] = *(const s16x8*)(Bs + (wn * 64 + ni * 16 + l15) * 40 + quad * 8);
    #pragma unroll
    for (int mi = 0; mi < 4; ++mi)
      #pragma unroll
      for (int ni = 0; ni < 4; ++ni)
        acc[mi][ni] = MFMA(af[mi], bf[ni], acc[mi][ni]);
  }
  #pragma unroll
  for (int mi = 0; mi < 4; ++mi)
    #pragma unroll
    for (int ni = 0; ni < 4; ++ni) {
      const int col = n0 + wn * 64 + ni * 16 + l15;
      const float bs = bias[col];
      #pragma unroll
      for (int r = 0; r < 4; ++r) {
        const int row = m0 + wm * 64 + mi * 16 + quad * 4 + r;
        C[(size_t)row * Ndim + col] = acc[mi][ni][r] + bs;
      }
    }
}

// ================= persistent recurrent LSTM =================
// blocks: 256 = 4 batch-tiles(64) x 64 h-slices(16 dims; all 4 gates per block)
// waves:  4 = (k-half) x (gate-pair); LDS exchange merges partials.
template<bool BEAT>
__global__ __launch_bounds__(256) void lstm_rec(
    const u16* __restrict__ Whh,   // [4096][1024] bf16
    const float* __restrict__ xg,  // [8192][4096] f32 rows = b*32 + m
    const u16* __restrict__ WihB,  // [4096][128]  (beat)
    const u16* __restrict__ inp,   // [256*512][128] (beat)
    const u16* __restrict__ linW,  // [128][1024]  (beat)
    const float* __restrict__ linb,// [128]        (beat)
    u16* __restrict__ hbuf0, u16* __restrict__ hbuf1,
    u16* __restrict__ aux,         // measure: lat [8192][1024]; beat: ring [32][256][1024]
    float* __restrict__ dout,      // beat: [256][512][128]
    unsigned* __restrict__ ctr)
{
  extern __shared__ char smem[];
  u16* sW = (u16*)smem;                         // 64 rows x (1024+8)
  float* sEx = (float*)(smem + 64 * 1032 * 2);  // 2 bufs x 64 x 33 floats

  const int blk = blockIdx.x;
  const int bt = blk >> 6, ht = blk & 63;
  const int tid = threadIdx.x;
  const int wave = tid >> 6, lane = tid & 63;
  const int quad = lane >> 4, l15 = lane & 15;
  const int kh = wave & 1, nh = wave >> 1;

  // stage Whh slice (rows {g*1024 + ht*16 + d}) into LDS, once
  for (int c = tid; c < 8192; c += 256) {
    const int rr = c >> 7;
    const int cc = (c & 127) << 3;
    const int gr = ((rr >> 4) << 10) + (ht << 4) + (rr & 15);
    *(s16x8*)(sW + rr * 1032 + cc) = *(const s16x8*)(Whh + ((size_t)gr << 10) + cc);
  }
  __syncthreads();

  const int batch_l = tid & 63, dgrp = tid >> 6;
  const int b_g = (bt << 6) + batch_l;
  float cst[4] = {0.f, 0.f, 0.f, 0.f};
  float xgv[4][4];

  const int T = BEAT ? 512 : 32;
  const u16* hbufs[2] = {hbuf0, hbuf1};

  for (int t = 0; t < T; ++t) {
    const u16* hp = hbufs[t & 1];
    u16* hn = const_cast<u16*>(hbufs[(t + 1) & 1]);

    if (!BEAT || (t & 15) == 0) {   // lat-projection slice (incl. bias), fp32
      const int mrow = BEAT ? (t >> 4) : t;
      const float* xr = xg + (size_t)(b_g * 32 + mrow) * 4096 + (ht << 4) + (dgrp << 2);
      #pragma unroll
      for (int g = 0; g < 4; ++g)
        #pragma unroll
        for (int j = 0; j < 4; ++j) xgv[g][j] = xr[g * 1024 + j];
    }

    f32x4 acc[4][2];
    #pragma unroll
    for (int mi = 0; mi < 4; ++mi)
      #pragma unroll
      for (int gi = 0; gi < 2; ++gi) { f32x4 z = {0.f,0.f,0.f,0.f}; acc[mi][gi] = z; }

    // recurrent part: this wave's K-half of h @ Whh^T
    for (int kc = 0; kc < 16; ++kc) {
      const int k = (kh << 9) + (kc << 5) + (quad << 3);
      s16x8 bfr0 = *(const s16x8*)(sW + (((nh * 2 + 0) << 4) + l15) * 1032 + k);
      s16x8 bfr1 = *(const s16x8*)(sW + (((nh * 2 + 1) << 4) + l15) * 1032 + k);
      #pragma unroll
      for (int mi = 0; mi < 4; ++mi) {
        s16x8 afr = *(const s16x8*)(hp + (((size_t)(bt << 6) + (mi << 4) + l15) << 10) + k);
        acc[mi][0] = MFMA(afr, bfr0, acc[mi][0]);
        acc[mi][1] = MFMA(afr, bfr1, acc[mi][1]);
      }
    }
    if (BEAT) {  // beat-input projection: inp[:,t,:] @ WihB^T (K=128)
      #pragma unroll
      for (int kc = 0; kc < 2; ++kc) {
        const int k = (kh << 6) + (kc << 5) + (quad << 3);
        s16x8 bfr0 = *(const s16x8*)(WihB + (size_t)(((nh * 2 + 0) << 10) + (ht << 4) + l15) * 128 + k);
        s16x8 bfr1 = *(const s16x8*)(WihB + (size_t)(((nh * 2 + 1) << 10) + (ht << 4) + l15) * 128 + k);
        #pragma unroll
        for (int mi = 0; mi < 4; ++mi) {
          s16x8 afr = *(const s16x8*)(inp + ((size_t)((bt << 6) + (mi << 4) + l15) * 512 + t) * 128 + k);
          acc[mi][0] = MFMA(afr, bfr0, acc[mi][0]);
          acc[mi][1] = MFMA(afr, bfr1, acc[mi][1]);
        }
      }
    }

    // merge k-halves via LDS
    if (kh == 1) {
      #pragma unroll
      for (int mi = 0; mi < 4; ++mi)
        #pragma unroll
        for (int gi = 0; gi < 2; ++gi)
          #pragma unroll
          for (int r = 0; r < 4; ++r)
            sEx[nh * 2112 + ((mi << 4) + (quad << 2) + r) * 33 + (gi << 4) + l15] = acc[mi][gi][r];
    }
    __syncthreads();
    if (kh == 0) {
      #pragma unroll
      for (int mi = 0; mi < 4; ++mi)
        #pragma unroll
        for (int gi = 0; gi < 2; ++gi)
          #pragma unroll
          for (int r = 0; r < 4; ++r) {
            const int idx = nh * 2112 + ((mi << 4) + (quad << 2) + r) * 33 + (gi << 4) + l15;
            sEx[idx] += acc[mi][gi][r];
          }
    }
    __syncthreads();

    // element-wise LSTM cell update (thread owns 4 dims of 1 batch)
    float hv[4], tv[4];
    {
      const int bo = batch_l * 33;
      #pragma unroll
      for (int j = 0; j < 4; ++j) {
        const int d = (dgrp << 2) + j;
        const float pi = sEx[bo + d]              + xgv[0][j];
        const float pf = sEx[bo + 16 + d]         + xgv[1][j];
        const float pg = sEx[2112 + bo + d]       + xgv[2][j];
        const float po = sEx[2112 + bo + 16 + d]  + xgv[3][j];
        const float iv = sigf(pi), fv = sigf(pf), gv = tanh_(pg), ov = sigf(po);
        cst[j] = fv * cst[j] + iv * gv;
        hv[j] = ov * tanh_(cst[j]);
        tv[j] = tanh_(hv[j]);
      }
    }
    uint2 hpk, tpk;
    hpk.x = (unsigned)f2bf(hv[0]) | ((unsigned)f2bf(hv[1]) << 16);
    hpk.y = (unsigned)f2bf(hv[2]) | ((unsigned)f2bf(hv[3]) << 16);
    tpk.x = (unsigned)f2bf(tv[0]) | ((unsigned)f2bf(tv[1]) << 16);
    tpk.y = (unsigned)f2bf(tv[2]) | ((unsigned)f2bf(tv[3]) << 16);
    *(uint2*)(hn + ((size_t)b_g << 10) + (ht << 4) + (dgrp << 2)) = hpk;
    if (BEAT)
      *(uint2*)(aux + ((size_t)((t & 31) * 256 + b_g) << 10) + (ht << 4) + (dgrp << 2)) = tpk;
    else
      *(uint2*)(aux + ((size_t)(b_g * 32 + t) << 10) + (ht << 4) + (dgrp << 2)) = tpk;

    // ---- grid barrier (device-scope, sense-free monotone counter) ----
    __syncthreads();
    if (tid == 0) {
      __hip_atomic_fetch_add(ctr, 1u, __ATOMIC_RELEASE, __HIP_MEMORY_SCOPE_AGENT);
      const unsigned tgt = 256u * (unsigned)(t + 1);
      while (__hip_atomic_load(ctr, __ATOMIC_RELAXED, __HIP_MEMORY_SCOPE_AGENT) < tgt)
        __builtin_amdgcn_s_sleep(1);
    }
    __syncthreads();
    (void)__hip_atomic_load(ctr, __ATOMIC_ACQUIRE, __HIP_MEMORY_SCOPE_AGENT); // per-thread acquire

    // ---- fused output projection, every 16 steps, on 64 duty blocks ----
    if (BEAT && ((t & 15) == 15) && ht < 16) {
      const int t0 = t - 15 + ht;
      const u16* Ar = aux + ((size_t)((t0 & 31) * 256 + (bt << 6)) << 10);
      f32x4 oacc[8];
      #pragma unroll
      for (int nt = 0; nt < 8; ++nt) { f32x4 z = {0.f,0.f,0.f,0.f}; oacc[nt] = z; }
      for (int kc = 0; kc < 32; ++kc) {
        const int k = (kc << 5) + (quad << 3);
        s16x8 a = *(const s16x8*)(Ar + (((size_t)(wave << 4) + l15) << 10) + k);
        #pragma unroll
        for (int nt = 0; nt < 8; ++nt) {
          s16x8 b = *(const s16x8*)(linW + (((size_t)(nt << 4) + l15) << 10) + k);
          oacc[nt] = MFMA(a, b, oacc[nt]);
        }
      }
      #pragma unroll
      for (int nt = 0; nt < 8; ++nt) {
        const int col = (nt << 4) + l15;
        const float bs = linb[col];
        #pragma unroll
        for (int r = 0; r < 4; ++r) {
          const int bg2 = (bt << 6) + (wave << 4) + (quad << 2) + r;
          dout[((size_t)bg2 * 512 + t0) * 128 + col] = oacc[nt][r] + bs;
        }
      }
    }
  }
}

// ================= launcher =================
extern "C" void kernel_launch(void* const* d_in, const int* in_sizes, int n_in,
                              void* d_out, int out_size, void* d_ws, size_t ws_size,
                              hipStream_t stream) {
  (void)in_sizes; (void)n_in; (void)out_size; (void)ws_size;
  const float* latent = (const float*)d_in[0];
  const float* inputs = (const float*)d_in[1];
  const float* mWih   = (const float*)d_in[2];
  const float* mWhh   = (const float*)d_in[3];
  const float* mb     = (const float*)d_in[4];
  const float* bWih   = (const float*)d_in[5];
  const float* bWhh   = (const float*)d_in[6];
  const float* bb     = (const float*)d_in[7];
  const float* linW   = (const float*)d_in[8];
  const float* linb   = (const float*)d_in[9];
  char* ws = (char*)d_ws;

  float* xg    = (float*)(ws + OFF_XG);
  u16* latb    = (u16*)(ws + OFF_LATB);
  u16* inpb    = (u16*)(ws + OFF_INPB);
  u16* mwihb   = (u16*)(ws + OFF_MWIH);
  u16* mwhhb   = (u16*)(ws + OFF_MWHH);
  u16* bwab    = (u16*)(ws + OFF_BWA);
  u16* bwbb    = (u16*)(ws + OFF_BWB);
  u16* bwhhb   = (u16*)(ws + OFF_BWHH);
  u16* linwb   = (u16*)(ws + OFF_LINW);
  u16* latT    = (u16*)(ws + OFF_LAT);
  u16* hm      = (u16*)(ws + OFF_HM);
  u16* hb      = (u16*)(ws + OFF_HB);
  u16* ring    = (u16*)(ws + OFF_RING);
  unsigned* cs = (unsigned*)(ws + OFF_CTR);

  constexpr unsigned SMEM = 64 * 1032 * 2 + 2 * 2112 * 4;  // 148,992 B
  hipFuncSetAttribute((const void*)(&lstm_rec<false>),
                      hipFuncAttributeMaxDynamicSharedMemorySize, (int)SMEM);
  hipFuncSetAttribute((const void*)(&lstm_rec<true>),
                      hipFuncAttributeMaxDynamicSharedMemorySize, (int)SMEM);

  // 1) prep: casts + splits + zero state/counters
  {
    const size_t total = 37355584ull;
    const int blocks = (int)((total + 255) / 256);
    prep_kernel<<<blocks, 256, 0, stream>>>(ws, latent, inputs, mWih, mWhh, bWih, bWhh, linW);
  }
  // 2) measure input projection: xg = latent @ mWih^T + mb   [8192x4096], K=512
  gemm_bt_bias<<<2048, 256, 0, stream>>>(latb, mwihb, mb, xg, 512, 4096);

  // 3) measure LSTM (T=32), writes lat = tanh(h)
  {
    const u16* a_whh = mwhhb; const float* a_xg = xg; const u16* a_wib = bwbb;
    const u16* a_inp = inpb;  const u16* a_lw = linwb; const float* a_lb = linb;
    u16* a_h0 = hm; u16* a_h1 = hm + Bz * Hz; u16* a_aux = latT;
    float* a_do = (float*)d_out; unsigned* a_ct = cs + 0;
    void* margs[] = {&a_whh, &a_xg, &a_wib, &a_inp, &a_lw, &a_lb,
                     &a_h0, &a_h1, &a_aux, &a_do, &a_ct};
    hipLaunchCooperativeKernel((const void*)(&lstm_rec<false>), dim3(256), dim3(256),
                               margs, SMEM, stream);
  }
  // 4) beat lat projection: xg = lat @ bWih[:, :1024]^T + bb   [8192x4096], K=1024
  gemm_bt_bias<<<2048, 256, 0, stream>>>(latT, bwab, bb, xg, 1024, 4096);

  // 5) beat LSTM (T=512) with fused input-projection + fused output linear
  {
    const u16* a_whh = bwhhb; const float* a_xg = xg; const u16* a_wib = bwbb;
    const u16* a_inp = inpb;  const u16* a_lw = linwb; const float* a_lb = linb;
    u16* a_h0 = hb; u16* a_h1 = hb + Bz * Hz; u16* a_aux = ring;
    float* a_do = (float*)d_out; unsigned* a_ct = cs + 16;
    void* bargs[] = {&a_whh, &a_xg, &a_wib, &a_inp, &a_lw, &a_lb,
                     &a_h0, &a_h1, &a_aux, &a_do, &a_ct};
    hipLaunchCooperativeKernel((const void*)(&lstm_rec<true>), dim3(256), dim3(256),
                               bargs, SMEM, stream);
  }
}

// Round 3
// 22389.204 us; speedup vs baseline: 1.0397x; 1.0397x over previous
//
#include <hip/hip_runtime.h>
#include <stdint.h>

typedef short s16x8 __attribute__((ext_vector_type(8)));
typedef float f32x4 __attribute__((ext_vector_type(4)));
typedef unsigned short u16;
typedef unsigned long long u64;

#define DEV static __device__ __forceinline__
#define SCOPE_AGENT __HIP_MEMORY_SCOPE_AGENT

DEV u16 f2bf(float f) {
  unsigned u = __float_as_uint(f);
  u = (u + 0x7FFFu + ((u >> 16) & 1u)) >> 16;   // RNE
  return (u16)u;
}
DEV float sigf(float x) { return 1.0f / (1.0f + __expf(-x)); }
DEV float tanh_(float x) { float e = __expf(2.0f * x); return 1.0f - 2.0f / (e + 1.0f); }
DEV f32x4 MFMA(s16x8 a, s16x8 b, f32x4 c) {
  return __builtin_amdgcn_mfma_f32_16x16x32_bf16(a, b, c, 0, 0, 0);
}
// relaxed agent-scope atomics: cache-bypassing (sc0 sc1), per-location coherent.
DEV u64 cload(const u64* p) {
  return __hip_atomic_load((u64*)p, __ATOMIC_RELAXED, SCOPE_AGENT);
}
DEV void cstore(u64* p, u64 v) {
  __hip_atomic_store(p, v, __ATOMIC_RELAXED, SCOPE_AGENT);
}
union U16x8 { u64 u[2]; s16x8 v; };

// ---------------- problem dims ----------------
constexpr int Bz = 256, INz = 512, Hz = 1024, Oz = 128;
constexpr int G4 = 4096;     // 4*H
constexpr int TB = 512;      // beat timesteps (M*S)
constexpr int BM = 8192;     // B*M rows

// ---------------- workspace layout (bytes) ----------------
constexpr size_t OFF_XG   = 0;                                   // f32 [8192][4096]
constexpr size_t OFF_LATB = OFF_XG   + (size_t)BM * G4 * 4;      // bf16 [8192][512]
constexpr size_t OFF_INPB = OFF_LATB + (size_t)BM * INz * 2;     // bf16 [256*512][128]
constexpr size_t OFF_MWIH = OFF_INPB + (size_t)Bz * TB * Oz * 2; // bf16 [4096][512]
constexpr size_t OFF_MWHH = OFF_MWIH + (size_t)G4 * INz * 2;     // bf16 [4096][1024]
constexpr size_t OFF_BWA  = OFF_MWHH + (size_t)G4 * Hz * 2;      // bf16 [4096][1024]
constexpr size_t OFF_BWB  = OFF_BWA  + (size_t)G4 * Hz * 2;      // bf16 [4096][128]
constexpr size_t OFF_BWHH = OFF_BWB  + (size_t)G4 * Oz * 2;      // bf16 [4096][1024]
constexpr size_t OFF_LINW = OFF_BWHH + (size_t)G4 * Hz * 2;      // bf16 [128][1024]
constexpr size_t OFF_LAT  = OFF_LINW + (size_t)Oz * Hz * 2;      // bf16 [8192][1024]
constexpr size_t OFF_HM   = OFF_LAT  + (size_t)BM * Hz * 2;      // bf16 2x[256][1024]
constexpr size_t OFF_HB   = OFF_HM   + (size_t)2 * Bz * Hz * 2;  // bf16 2x[256][1024]
constexpr size_t OFF_RING = OFF_HB   + (size_t)2 * Bz * Hz * 2;  // bf16 [32][256][1024]
constexpr size_t OFF_CTR  = OFF_RING + (size_t)32 * Bz * Hz * 2; // counters (64 u32)

// ================= prep: casts / splits / zeroing =================
__global__ __launch_bounds__(256) void prep_kernel(
    char* __restrict__ ws, const float* __restrict__ latent,
    const float* __restrict__ inputs, const float* __restrict__ mWih,
    const float* __restrict__ mWhh, const float* __restrict__ bWih,
    const float* __restrict__ bWhh, const float* __restrict__ linW)
{
  size_t i = (size_t)blockIdx.x * 256 + threadIdx.x;
  const size_t n0 = (size_t)BM * INz;
  const size_t n1 = (size_t)Bz * TB * Oz;
  const size_t n2 = (size_t)G4 * INz;
  const size_t n3 = (size_t)G4 * Hz;
  const size_t n4 = (size_t)G4 * (Hz + Oz);
  const size_t n5 = (size_t)G4 * Hz;
  const size_t n6 = (size_t)Oz * Hz;
  const size_t n7 = (size_t)2 * Bz * Hz;
  const size_t n8 = (size_t)2 * Bz * Hz;
  const size_t n9 = 64;
  if (i < n0) { ((u16*)(ws + OFF_LATB))[i] = f2bf(latent[i]); return; } i -= n0;
  if (i < n1) { ((u16*)(ws + OFF_INPB))[i] = f2bf(inputs[i]); return; } i -= n1;
  if (i < n2) { ((u16*)(ws + OFF_MWIH))[i] = f2bf(mWih[i]);   return; } i -= n2;
  if (i < n3) { ((u16*)(ws + OFF_MWHH))[i] = f2bf(mWhh[i]);   return; } i -= n3;
  if (i < n4) {
    size_t r = i / 1152, c = i - r * 1152;
    float v = bWih[i];
    if (c < 1024) ((u16*)(ws + OFF_BWA))[r * 1024 + c] = f2bf(v);
    else          ((u16*)(ws + OFF_BWB))[r * 128 + (c - 1024)] = f2bf(v);
    return;
  } i -= n4;
  if (i < n5) { ((u16*)(ws + OFF_BWHH))[i] = f2bf(bWhh[i]);   return; } i -= n5;
  if (i < n6) { ((u16*)(ws + OFF_LINW))[i] = f2bf(linW[i]);   return; } i -= n6;
  if (i < n7) { ((u16*)(ws + OFF_HM))[i] = 0; return; } i -= n7;
  if (i < n8) { ((u16*)(ws + OFF_HB))[i] = 0; return; } i -= n8;
  if (i < n9) { ((unsigned*)(ws + OFF_CTR))[i] = 0; return; }
}

// ================= projection GEMM: C[M][N](f32) = A[M][K](bf16) @ B[N][K]^T + bias =================
__global__ __launch_bounds__(256) void gemm_bt_bias(
    const u16* __restrict__ A, const u16* __restrict__ Bw,
    const float* __restrict__ bias, float* __restrict__ C, int K, int Ndim)
{
  __shared__ u16 As[128 * 40];
  __shared__ u16 Bs[128 * 40];
  const int bx = blockIdx.x & 63;
  const int by = blockIdx.x >> 6;
  const int m0 = bx * 128, n0 = by * 128;
  const int tid = threadIdx.x, lane = tid & 63, wave = tid >> 6;
  const int quad = lane >> 4, l15 = lane & 15;
  const int wm = wave & 1, wn = wave >> 1;
  const int srow = tid >> 1, shalf = tid & 1;

  f32x4 acc[4][4];
  #pragma unroll
  for (int mi = 0; mi < 4; ++mi)
    #pragma unroll
    for (int ni = 0; ni < 4; ++ni) { f32x4 z = {0.f,0.f,0.f,0.f}; acc[mi][ni] = z; }

  const int KC = K >> 5;
  for (int kc = 0; kc < KC; ++kc) {
    const size_t ka = (size_t)(m0 + srow) * K + kc * 32 + shalf * 16;
    s16x8 va0 = *(const s16x8*)(A + ka);
    s16x8 va1 = *(const s16x8*)(A + ka + 8);
    const size_t kb = (size_t)(n0 + srow) * K + kc * 32 + shalf * 16;
    s16x8 vb0 = *(const s16x8*)(Bw + kb);
    s16x8 vb1 = *(const s16x8*)(Bw + kb + 8);
    __syncthreads();
    *(s16x8*)(As + srow * 40 + shalf * 16)     = va0;
    *(s16x8*)(As + srow * 40 + shalf * 16 + 8) = va1;
    *(s16x8*)(Bs + srow * 40 + shalf * 16)     = vb0;
    *(s16x8*)(Bs + srow * 40 + shalf * 16 + 8) = vb1;
    __syncthreads();
    s16x8 af[4], bf[4];
    #pragma unroll
    for (int mi = 0; mi < 4; ++mi)
      af[mi] = *(const s16x8*)(As + (wm * 64 + mi * 16 + l15) * 40 + quad * 8);
    #pragma unroll
    for (int ni = 0; ni < 4; ++ni)
      bf[ni] = *(const s16x8*)(Bs + (wn * 64 + ni * 16 + l15) * 40 + quad * 8);
    #pragma unroll
    for (int mi = 0; mi < 4; ++mi)
      #pragma unroll
      for (int ni = 0; ni < 4; ++ni)
        acc[mi][ni] = MFMA(af[mi], bf[ni], acc[mi][ni]);
  }
  #pragma unroll
  for (int mi = 0; mi < 4; ++mi)
    #pragma unroll
    for (int ni = 0; ni < 4; ++ni) {
      const int col = n0 + wn * 64 + ni * 16 + l15;
      const float bs = bias[col];
      #pragma unroll
      for (int r = 0; r < 4; ++r) {
        const int row = m0 + wm * 64 + mi * 16 + quad * 4 + r;
        C[(size_t)row * Ndim + col] = acc[mi][ni][r] + bs;
      }
    }
}

// ================= persistent recurrent LSTM =================
// R1 structure: blocks 256 = 4 batch-tiles(64) x 64 h-slices; Whh slice in LDS;
// waves = (k-half) x (gate-pair); LDS exchange merges partials.
// R3 delta: h/ring traffic via relaxed agent atomics (cache-bypassing);
// barrier keeps release-add + ONE tid0 acquire per block (insurance).
template<bool BEAT>
__global__ __launch_bounds__(256) void lstm_rec(
    const u16* __restrict__ Whh,   // [4096][1024] bf16
    const float* __restrict__ xg,  // [8192][4096] f32 rows = b*32 + m
    const u16* __restrict__ WihB,  // [4096][128]  (beat)
    const u16* __restrict__ inp,   // [256*512][128] (beat)
    const u16* __restrict__ linW,  // [128][1024]  (beat)
    const float* __restrict__ linb,// [128]        (beat)
    u16* __restrict__ hbuf0, u16* __restrict__ hbuf1,
    u16* __restrict__ aux,         // measure: lat [8192][1024]; beat: ring [32][256][1024]
    float* __restrict__ dout,      // beat: [256][512][128]
    unsigned* __restrict__ ctr)
{
  extern __shared__ char smem[];
  u16* sW = (u16*)smem;                         // 64 rows x (1024+8)
  float* sEx = (float*)(smem + 64 * 1032 * 2);  // 2 bufs x 64 x 33 floats

  const int blk = blockIdx.x;
  const int bt = blk >> 6, ht = blk & 63;
  const int tid = threadIdx.x;
  const int wave = tid >> 6, lane = tid & 63;
  const int quad = lane >> 4, l15 = lane & 15;
  const int kh = wave & 1, nh = wave >> 1;

  // stage Whh slice (rows {g*1024 + ht*16 + d}) into LDS, once
  for (int c = tid; c < 8192; c += 256) {
    const int rr = c >> 7;
    const int cc = (c & 127) << 3;
    const int gr = ((rr >> 4) << 10) + (ht << 4) + (rr & 15);
    *(s16x8*)(sW + rr * 1032 + cc) = *(const s16x8*)(Whh + ((size_t)gr << 10) + cc);
  }
  __syncthreads();

  const int batch_l = tid & 63, dgrp = tid >> 6;
  const int b_g = (bt << 6) + batch_l;
  float cst[4] = {0.f, 0.f, 0.f, 0.f};
  float xgv[4][4];

  const int T = BEAT ? 512 : 32;
  const u16* hbufs[2] = {hbuf0, hbuf1};

  for (int t = 0; t < T; ++t) {
    const u16* hp = hbufs[t & 1];
    u16* hn = const_cast<u16*>(hbufs[(t + 1) & 1]);

    if (!BEAT || (t & 15) == 0) {   // lat-projection slice (incl. bias), fp32
      const int mrow = BEAT ? (t >> 4) : t;
      const float* xr = xg + (size_t)(b_g * 32 + mrow) * 4096 + (ht << 4) + (dgrp << 2);
      #pragma unroll
      for (int g = 0; g < 4; ++g)
        #pragma unroll
        for (int j = 0; j < 4; ++j) xgv[g][j] = xr[g * 1024 + j];
    }

    f32x4 acc[4][2];
    #pragma unroll
    for (int mi = 0; mi < 4; ++mi)
      #pragma unroll
      for (int gi = 0; gi < 2; ++gi) { f32x4 z = {0.f,0.f,0.f,0.f}; acc[mi][gi] = z; }

    // recurrent part: this wave's K-half of h @ Whh^T (h via coherent loads)
    const u64* hq = (const u64*)hp + ((size_t)(bt << 6) << 8);
    for (int kc = 0; kc < 16; ++kc) {
      const int k = (kh << 9) + (kc << 5) + (quad << 3);
      s16x8 bfr0 = *(const s16x8*)(sW + (((nh * 2 + 0) << 4) + l15) * 1032 + k);
      s16x8 bfr1 = *(const s16x8*)(sW + (((nh * 2 + 1) << 4) + l15) * 1032 + k);
      #pragma unroll
      for (int mi = 0; mi < 4; ++mi) {
        const u64* p = hq + (((size_t)(mi << 4) + l15) << 8) + (k >> 2);
        U16x8 af;
        af.u[0] = cload(p);
        af.u[1] = cload(p + 1);
        acc[mi][0] = MFMA(af.v, bfr0, acc[mi][0]);
        acc[mi][1] = MFMA(af.v, bfr1, acc[mi][1]);
      }
    }
    if (BEAT) {  // beat-input projection: inp[:,t,:] @ WihB^T (K=128)
      #pragma unroll
      for (int kc = 0; kc < 2; ++kc) {
        const int k = (kh << 6) + (kc << 5) + (quad << 3);
        s16x8 bfr0 = *(const s16x8*)(WihB + (size_t)(((nh * 2 + 0) << 10) + (ht << 4) + l15) * 128 + k);
        s16x8 bfr1 = *(const s16x8*)(WihB + (size_t)(((nh * 2 + 1) << 10) + (ht << 4) + l15) * 128 + k);
        #pragma unroll
        for (int mi = 0; mi < 4; ++mi) {
          s16x8 afr = *(const s16x8*)(inp + ((size_t)((bt << 6) + (mi << 4) + l15) * 512 + t) * 128 + k);
          acc[mi][0] = MFMA(afr, bfr0, acc[mi][0]);
          acc[mi][1] = MFMA(afr, bfr1, acc[mi][1]);
        }
      }
    }

    // merge k-halves via LDS
    if (kh == 1) {
      #pragma unroll
      for (int mi = 0; mi < 4; ++mi)
        #pragma unroll
        for (int gi = 0; gi < 2; ++gi)
          #pragma unroll
          for (int r = 0; r < 4; ++r)
            sEx[nh * 2112 + ((mi << 4) + (quad << 2) + r) * 33 + (gi << 4) + l15] = acc[mi][gi][r];
    }
    __syncthreads();
    if (kh == 0) {
      #pragma unroll
      for (int mi = 0; mi < 4; ++mi)
        #pragma unroll
        for (int gi = 0; gi < 2; ++gi)
          #pragma unroll
          for (int r = 0; r < 4; ++r) {
            const int idx = nh * 2112 + ((mi << 4) + (quad << 2) + r) * 33 + (gi << 4) + l15;
            sEx[idx] += acc[mi][gi][r];
          }
    }
    __syncthreads();

    // element-wise LSTM cell update (thread owns 4 dims of 1 batch)
    float hv[4], tv[4];
    {
      const int bo = batch_l * 33;
      #pragma unroll
      for (int j = 0; j < 4; ++j) {
        const int d = (dgrp << 2) + j;
        const float pi = sEx[bo + d]              + xgv[0][j];
        const float pf = sEx[bo + 16 + d]         + xgv[1][j];
        const float pg = sEx[2112 + bo + d]       + xgv[2][j];
        const float po = sEx[2112 + bo + 16 + d]  + xgv[3][j];
        const float iv = sigf(pi), fv = sigf(pf), gv = tanh_(pg), ov = sigf(po);
        cst[j] = fv * cst[j] + iv * gv;
        hv[j] = ov * tanh_(cst[j]);
        tv[j] = tanh_(hv[j]);
      }
    }
    u64 hpk = (u64)f2bf(hv[0]) | ((u64)f2bf(hv[1]) << 16)
            | ((u64)f2bf(hv[2]) << 32) | ((u64)f2bf(hv[3]) << 48);
    u64 tpk = (u64)f2bf(tv[0]) | ((u64)f2bf(tv[1]) << 16)
            | ((u64)f2bf(tv[2]) << 32) | ((u64)f2bf(tv[3]) << 48);
    cstore((u64*)(hn + ((size_t)b_g << 10) + (ht << 4) + (dgrp << 2)), hpk);
    if (BEAT)
      cstore((u64*)(aux + ((size_t)((t & 31) * 256 + b_g) << 10) + (ht << 4) + (dgrp << 2)), tpk);
    else
      cstore((u64*)(aux + ((size_t)(b_g * 32 + t) << 10) + (ht << 4) + (dgrp << 2)), tpk);

    // ---- grid barrier: release-add, relaxed spin, ONE acquire per block ----
    __syncthreads();
    if (tid == 0) {
      __hip_atomic_fetch_add(ctr, 1u, __ATOMIC_RELEASE, SCOPE_AGENT);
      const unsigned tgt = 256u * (unsigned)(t + 1);
      while (__hip_atomic_load(ctr, __ATOMIC_RELAXED, SCOPE_AGENT) < tgt)
        __builtin_amdgcn_s_sleep(1);
      (void)__hip_atomic_load(ctr, __ATOMIC_ACQUIRE, SCOPE_AGENT);
    }
    __syncthreads();
    __atomic_signal_fence(__ATOMIC_SEQ_CST);

    // ---- fused output projection, every 16 steps, on 64 duty blocks ----
    if (BEAT && ((t & 15) == 15) && ht < 16) {
      const int t0 = t - 15 + ht;
      const u64* Arq = (const u64*)aux + (((size_t)((t0 & 31) * 256 + (bt << 6))) << 8);
      f32x4 oacc[8];
      #pragma unroll
      for (int nt = 0; nt < 8; ++nt) { f32x4 z = {0.f,0.f,0.f,0.f}; oacc[nt] = z; }
      for (int kc = 0; kc < 32; ++kc) {
        const u64* p = Arq + ((((size_t)wave << 4) + l15) << 8) + (kc << 3) + (quad << 1);
        U16x8 af;
        af.u[0] = cload(p);
        af.u[1] = cload(p + 1);
        #pragma unroll
        for (int nt = 0; nt < 8; ++nt) {
          s16x8 b = *(const s16x8*)(linW + (((size_t)(nt << 4) + l15) << 10) + (kc << 5) + (quad << 3));
          oacc[nt] = MFMA(af.v, b, oacc[nt]);
        }
      }
      #pragma unroll
      for (int nt = 0; nt < 8; ++nt) {
        const int col = (nt << 4) + l15;
        const float bs = linb[col];
        #pragma unroll
        for (int r = 0; r < 4; ++r) {
          const int bg2 = (bt << 6) + (wave << 4) + (quad << 2) + r;
          dout[((size_t)bg2 * 512 + t0) * 128 + col] = oacc[nt][r] + bs;
        }
      }
    }
  }
}

// ================= launcher =================
extern "C" void kernel_launch(void* const* d_in, const int* in_sizes, int n_in,
                              void* d_out, int out_size, void* d_ws, size_t ws_size,
                              hipStream_t stream) {
  (void)in_sizes; (void)n_in; (void)out_size; (void)ws_size;
  const float* latent = (const float*)d_in[0];
  const float* inputs = (const float*)d_in[1];
  const float* mWih   = (const float*)d_in[2];
  const float* mWhh   = (const float*)d_in[3];
  const float* mb     = (const float*)d_in[4];
  const float* bWih   = (const float*)d_in[5];
  const float* bWhh   = (const float*)d_in[6];
  const float* bb     = (const float*)d_in[7];
  const float* linW   = (const float*)d_in[8];
  const float* linb   = (const float*)d_in[9];
  char* ws = (char*)d_ws;

  float* xg    = (float*)(ws + OFF_XG);
  u16* latb    = (u16*)(ws + OFF_LATB);
  u16* inpb    = (u16*)(ws + OFF_INPB);
  u16* mwihb   = (u16*)(ws + OFF_MWIH);
  u16* mwhhb   = (u16*)(ws + OFF_MWHH);
  u16* bwab    = (u16*)(ws + OFF_BWA);
  u16* bwbb    = (u16*)(ws + OFF_BWB);
  u16* bwhhb   = (u16*)(ws + OFF_BWHH);
  u16* linwb   = (u16*)(ws + OFF_LINW);
  u16* latT    = (u16*)(ws + OFF_LAT);
  u16* hm      = (u16*)(ws + OFF_HM);
  u16* hb      = (u16*)(ws + OFF_HB);
  u16* ring    = (u16*)(ws + OFF_RING);
  unsigned* cs = (unsigned*)(ws + OFF_CTR);

  constexpr unsigned SMEM = 64 * 1032 * 2 + 2 * 2112 * 4;  // 148,992 B
  hipFuncSetAttribute((const void*)(&lstm_rec<false>),
                      hipFuncAttributeMaxDynamicSharedMemorySize, (int)SMEM);
  hipFuncSetAttribute((const void*)(&lstm_rec<true>),
                      hipFuncAttributeMaxDynamicSharedMemorySize, (int)SMEM);

  // 1) prep: casts + splits + zero state/counters
  {
    const size_t total = 37355584ull;
    const int blocks = (int)((total + 255) / 256);
    prep_kernel<<<blocks, 256, 0, stream>>>(ws, latent, inputs, mWih, mWhh, bWih, bWhh, linW);
  }
  // 2) measure input projection: xg = latent @ mWih^T + mb   [8192x4096], K=512
  gemm_bt_bias<<<2048, 256, 0, stream>>>(latb, mwihb, mb, xg, 512, 4096);

  // 3) measure LSTM (T=32), writes lat = tanh(h)
  {
    const u16* a_whh = mwhhb; const float* a_xg = xg; const u16* a_wib = bwbb;
    const u16* a_inp = inpb;  const u16* a_lw = linwb; const float* a_lb = linb;
    u16* a_h0 = hm; u16* a_h1 = hm + Bz * Hz; u16* a_aux = latT;
    float* a_do = (float*)d_out; unsigned* a_ct = cs;
    void* margs[] = {&a_whh, &a_xg, &a_wib, &a_inp, &a_lw, &a_lb,
                     &a_h0, &a_h1, &a_aux, &a_do, &a_ct};
    hipError_t e = hipLaunchCooperativeKernel((const void*)(&lstm_rec<false>),
                                              dim3(256), dim3(256), margs, SMEM, stream);
    if (e != hipSuccess) {
      // fallback: plain launch (1 block/CU via 149KB LDS -> co-resident)
      lstm_rec<false><<<256, 256, SMEM, stream>>>(mwhhb, xg, bwbb, inpb, linwb, linb,
                                                  hm, hm + Bz * Hz, latT,
                                                  (float*)d_out, cs);
    }
  }
  // 4) beat lat projection: xg = lat @ bWih[:, :1024]^T + bb   [8192x4096], K=1024
  gemm_bt_bias<<<2048, 256, 0, stream>>>(latT, bwab, bb, xg, 1024, 4096);

  // 5) beat LSTM (T=512) with fused input-projection + fused output linear
  {
    const u16* a_whh = bwhhb; const float* a_xg = xg; const u16* a_wib = bwbb;
    const u16* a_inp = inpb;  const u16* a_lw = linwb; const float* a_lb = linb;
    u16* a_h0 = hb; u16* a_h1 = hb + Bz * Hz; u16* a_aux = ring;
    float* a_do = (float*)d_out; unsigned* a_ct = cs + 16;
    void* bargs[] = {&a_whh, &a_xg, &a_wib, &a_inp, &a_lw, &a_lb,
                     &a_h0, &a_h1, &a_aux, &a_do, &a_ct};
    hipError_t e = hipLaunchCooperativeKernel((const void*)(&lstm_rec<true>),
                                              dim3(256), dim3(256), bargs, SMEM, stream);
    if (e != hipSuccess) {
      lstm_rec<true><<<256, 256, SMEM, stream>>>(bwhhb, xg, bwbb, inpb, linwb, linb,
                                                 hb, hb + Bz * Hz, ring,
                                                 (float*)d_out, cs + 16);
    }
  }
}